// Round 6
// baseline (467.464 us; speedup 1.0000x reference)
//
#include <hip/hip_runtime.h>
#include <hip/hip_bf16.h>
#include <stdint.h>

typedef __attribute__((ext_vector_type(4))) float f32x4;
typedef __attribute__((ext_vector_type(8))) short bf16x8;
typedef __attribute__((ext_vector_type(8))) unsigned short u16x8;

__device__ __forceinline__ unsigned short f2bf(float f) {
  unsigned int u = __float_as_uint(f);
  u += 0x7fffu + ((u >> 16) & 1u);   // round-to-nearest-even
  return (unsigned short)(u >> 16);
}

__device__ __forceinline__ unsigned int pk_bf16(float lo, float hi) {
  unsigned int r;
  asm("v_cvt_pk_bf16_f32 %0, %1, %2" : "=v"(r) : "v"(lo), "v"(hi));
  return r;
}

__global__ __launch_bounds__(256) void cvt_kernel(const float* __restrict__ in,
                                                  unsigned short* __restrict__ out, int n4) {
  int stride = gridDim.x * blockDim.x;
  for (int i = blockIdx.x * blockDim.x + threadIdx.x; i < n4; i += stride) {
    float4 v = reinterpret_cast<const float4*>(in)[i];
    ushort4 o;
    o.x = f2bf(v.x); o.y = f2bf(v.y); o.z = f2bf(v.z); o.w = f2bf(v.w);
    reinterpret_cast<ushort4*>(out)[i] = o;
  }
}

// C = A[M,Kd] * Bt[N,Kd]^T ; f32 accumulate. BM=128, BN=64 (grid 2 blocks/CU).
// AF32: A is float32, converted to bf16 during LDS staging.
// EPI 0: bf16 store row-major, value * scl
// EPI 1: V-transpose bf16 store: dst[(b*1024 + n)*2048 + (m&2047)]
// EPI 2: f32 store row-major with +bias[n]  (final output)
template <int EPI, int AF32>
__global__ __launch_bounds__(256) void gemm_bt(const void* __restrict__ Av,
                                               const unsigned short* __restrict__ Bt,
                                               unsigned short* __restrict__ C,
                                               float* __restrict__ Cf,
                                               const float* __restrict__ bias,
                                               float scl, int M, int N, int Kd) {
  __shared__ unsigned short As[128 * 64];
  __shared__ unsigned short Bs[64 * 64];
  const int tid = threadIdx.x;
  const int lane = tid & 63;
  const int wid = tid >> 6;
  const int wm = wid >> 1, wn = wid & 1;
  const int lc = lane & 15, qr = lane >> 4;
  const int m0 = blockIdx.x * 128, n0 = blockIdx.y * 64;

  f32x4 acc[4][2];
#pragma unroll
  for (int i = 0; i < 4; i++)
#pragma unroll
    for (int j = 0; j < 2; j++) acc[i][j] = (f32x4)0.0f;

  for (int k0 = 0; k0 < Kd; k0 += 64) {
#pragma unroll
    for (int i = 0; i < 4; i++) {
      int c = i * 256 + tid;          // 0..1023
      int row = c >> 3;               // 0..127
      int col = (c & 7) << 3;         // 0..56
      if (AF32) {
        const float* ap = &((const float*)Av)[(size_t)(m0 + row) * Kd + k0 + col];
        float4 v0 = *reinterpret_cast<const float4*>(ap);
        float4 v1 = *reinterpret_cast<const float4*>(ap + 4);
        u16x8 o;
        o[0] = f2bf(v0.x); o[1] = f2bf(v0.y); o[2] = f2bf(v0.z); o[3] = f2bf(v0.w);
        o[4] = f2bf(v1.x); o[5] = f2bf(v1.y); o[6] = f2bf(v1.z); o[7] = f2bf(v1.w);
        *reinterpret_cast<u16x8*>(&As[row * 64 + col]) = o;
      } else {
        *reinterpret_cast<u16x8*>(&As[row * 64 + col]) =
            *reinterpret_cast<const u16x8*>(
                &((const unsigned short*)Av)[(size_t)(m0 + row) * Kd + k0 + col]);
      }
    }
#pragma unroll
    for (int i = 0; i < 2; i++) {
      int c = i * 256 + tid;          // 0..511
      int row = c >> 3;               // 0..63
      int col = (c & 7) << 3;
      *reinterpret_cast<u16x8*>(&Bs[row * 64 + col]) =
          *reinterpret_cast<const u16x8*>(&Bt[(size_t)(n0 + row) * Kd + k0 + col]);
    }
    __syncthreads();
#pragma unroll
    for (int kk = 0; kk < 2; kk++) {
      bf16x8 a[4], b[2];
#pragma unroll
      for (int mf = 0; mf < 4; mf++)
        a[mf] = *reinterpret_cast<const bf16x8*>(&As[(wm * 64 + mf * 16 + lc) * 64 + kk * 32 + qr * 8]);
#pragma unroll
      for (int nf = 0; nf < 2; nf++)
        b[nf] = *reinterpret_cast<const bf16x8*>(&Bs[(wn * 32 + nf * 16 + lc) * 64 + kk * 32 + qr * 8]);
#pragma unroll
      for (int mf = 0; mf < 4; mf++)
#pragma unroll
        for (int nf = 0; nf < 2; nf++)
          acc[mf][nf] = __builtin_amdgcn_mfma_f32_16x16x32_bf16(a[mf], b[nf], acc[mf][nf], 0, 0, 0);
    }
    __syncthreads();
  }

#pragma unroll
  for (int mf = 0; mf < 4; mf++) {
#pragma unroll
    for (int nf = 0; nf < 2; nf++) {
      const int row0 = m0 + wm * 64 + mf * 16 + qr * 4;
      const int col = n0 + wn * 32 + nf * 16 + lc;
#pragma unroll
      for (int r = 0; r < 4; r++) {
        float v = acc[mf][nf][r];
        int row = row0 + r;
        if (EPI == 0) {
          C[(size_t)row * N + col] = f2bf(v * scl);
        } else if (EPI == 1) {
          int bb = row >> 11, s2 = row & 2047;
          C[((size_t)(bb * 1024 + col)) * 2048 + s2] = f2bf(v);
        } else {
          Cf[(size_t)row * N + col] = v + bias[col];
        }
      }
    }
  }
}

// Swapped-operand flash cross-attention: S^T = mfma(K, Q) so each lane owns
// ONE q-row (q = lane&15) and 16 keys/tile -> all softmax state is per-lane
// scalar; row reduce = in-lane tree + 2 shfl_xor. PV: O^T = mfma(V^T, P).
// W loads: per-lane nontemporal dwordx4, aligned with p registers.
// Q pre-scaled by 0.125 in its GEMM epilogue. 4 independent waves/block.
__global__ __launch_bounds__(256, 3) void flash_kernel(const unsigned short* __restrict__ Qg,
                                                       const unsigned short* __restrict__ Kg,
                                                       const unsigned short* __restrict__ Vt,
                                                       const float* __restrict__ Wm,
                                                       const int* __restrict__ mask,
                                                       unsigned short* __restrict__ Og) {
  __shared__ unsigned short P_lds[4][16][72];   // [wave][q][key] bf16, 144B rows (16B-aligned)
  const int tid = threadIdx.x;
  const int lane = tid & 63;
  const int wid = tid >> 6;
  const int lc = lane & 15, qr = lane >> 4;

  const int bx = blockIdx.x;
  const int nid = (bx & 7) * 128 + (bx >> 3);   // XCD swizzle: 4 heads per XCD
  const int b = nid >> 9, h = (nid >> 5) & 15, qt = nid & 31;
  const int q0 = qt * 64 + wid * 16;

  // Q fragments (B-operand now): lane holds Q[q=lc, k=kk*32+qr*8+j]
  bf16x8 aq[2];
#pragma unroll
  for (int kk = 0; kk < 2; kk++)
    aq[kk] = *reinterpret_cast<const bf16x8*>(
        &Qg[(size_t)(b * 2048 + q0 + lc) * 1024 + h * 64 + kk * 32 + qr * 8]);

  const float mbias = mask[b * 2048 + q0 + lc] ? 0.0f : -INFINITY;

  float m_run = -INFINITY, l_run = 0.0f;
  f32x4 o_acc[4];
#pragma unroll
  for (int vf = 0; vf < 4; vf++) o_acc[vf] = (f32x4)0.0f;

  const unsigned short* Kb = Kg + (size_t)(b * 2048) * 1024 + h * 64;
  const unsigned short* Vb = Vt + (size_t)(b * 1024 + h * 64) * 2048;
  const float* wrow = Wm + ((size_t)((b * 16 + h) * 2048 + q0 + lc)) * 2048 + qr * 4;

  bf16x8 kf[8];      // K A-frags: kf[f*2+kk] = K[s=s0+16f+lc, k=kk*32+qr*8+j]
  bf16x8 vr[8];      // V^T A-frags: vr[vf*2+kk] = V^T[v=vf*16+lc, s=s0+kk*32+qr*8+j]
  f32x4 wA[4], wB[4];  // W double buffer: w[f][r] = W[q=lc, s0+16f+4qr+r]

#define LOADK(S0)                                                           \
  _Pragma("unroll") for (int f = 0; f < 4; f++)                             \
  _Pragma("unroll") for (int kk = 0; kk < 2; kk++)                          \
      kf[f * 2 + kk] = *reinterpret_cast<const bf16x8*>(                    \
          &Kb[(size_t)((S0) + f * 16 + lc) * 1024 + kk * 32 + qr * 8]);

#define LOADV(S0)                                                           \
  _Pragma("unroll") for (int vf = 0; vf < 4; vf++)                         \
  _Pragma("unroll") for (int kk = 0; kk < 2; kk++)                          \
      vr[vf * 2 + kk] = *reinterpret_cast<const bf16x8*>(                   \
          &Vb[(size_t)(vf * 16 + lc) * 2048 + (S0) + kk * 32 + qr * 8]);

#define LOADW(S0, W)                                                        \
  _Pragma("unroll") for (int f = 0; f < 4; f++)                             \
      W[f] = __builtin_nontemporal_load(                                    \
          reinterpret_cast<const f32x4*>(wrow + (S0) + f * 16));

#define TILE(T, WC, WN)                                                     \
  {                                                                         \
    const int s0 = (T) * 64;                                                \
    if ((T) < 31) { LOADW(s0 + 64, WN); }                                   \
    f32x4 sacc[4];                                                          \
    _Pragma("unroll") for (int f = 0; f < 4; f++) sacc[f] = (f32x4)0.0f;    \
    _Pragma("unroll") for (int f = 0; f < 4; f++)                           \
    _Pragma("unroll") for (int kk = 0; kk < 2; kk++)                        \
        sacc[f] = __builtin_amdgcn_mfma_f32_16x16x32_bf16(                  \
            kf[f * 2 + kk], aq[kk], sacc[f], 0, 0, 0);                      \
    if ((T) < 31) { LOADK(s0 + 64); }                                       \
    float p[16];                                                            \
    float tm = -INFINITY;                                                   \
    _Pragma("unroll") for (int f = 0; f < 4; f++)                           \
    _Pragma("unroll") for (int r = 0; r < 4; r++) {                         \
      float v = fmaf(sacc[f][r], WC[f][r], mbias);                          \
      p[f * 4 + r] = v;                                                     \
      tm = fmaxf(tm, v);                                                    \
    }                                                                       \
    tm = fmaxf(tm, __shfl_xor(tm, 16));                                     \
    tm = fmaxf(tm, __shfl_xor(tm, 32));                                     \
    const float mn = fmaxf(m_run, tm);                                      \
    const float sc = __expf(m_run - mn);                                    \
    m_run = mn;                                                             \
    float rs = 0.0f;                                                        \
    _Pragma("unroll") for (int i = 0; i < 16; i++) {                        \
      p[i] = __expf(p[i] - mn);                                             \
      rs += p[i];                                                           \
    }                                                                       \
    rs += __shfl_xor(rs, 16);                                               \
    rs += __shfl_xor(rs, 32);                                               \
    l_run = l_run * sc + rs;                                                \
    _Pragma("unroll") for (int vf = 0; vf < 4; vf++)                        \
    _Pragma("unroll") for (int r = 0; r < 4; r++) o_acc[vf][r] *= sc;       \
    _Pragma("unroll") for (int f = 0; f < 4; f++) {                         \
      unsigned int u0 = pk_bf16(p[f * 4 + 0], p[f * 4 + 1]);                \
      unsigned int u1 = pk_bf16(p[f * 4 + 2], p[f * 4 + 3]);                \
      const int kb = f * 16 + qr * 4;                                       \
      *reinterpret_cast<unsigned int*>(&P_lds[wid][lc][kb]) = u0;           \
      *reinterpret_cast<unsigned int*>(&P_lds[wid][lc][kb + 2]) = u1;       \
    }                                                                       \
    _Pragma("unroll") for (int kk = 0; kk < 2; kk++) {                      \
      bf16x8 pb = *reinterpret_cast<const bf16x8*>(                         \
          &P_lds[wid][lc][kk * 32 + qr * 8]);                               \
      _Pragma("unroll") for (int vf = 0; vf < 4; vf++)                      \
          o_acc[vf] = __builtin_amdgcn_mfma_f32_16x16x32_bf16(              \
              vr[vf * 2 + kk], pb, o_acc[vf], 0, 0, 0);                     \
    }                                                                       \
    if ((T) < 31) { LOADV(s0 + 64); }                                       \
  }

  LOADW(0, wA);
  LOADK(0);
  LOADV(0);
#pragma unroll 1
  for (int t = 0; t < 32; t += 2) {
    TILE(t, wA, wB);
    TILE(t + 1, wB, wA);
  }

  const float inv = 1.0f / l_run;
#pragma unroll
  for (int vf = 0; vf < 4; vf++)
#pragma unroll
    for (int r = 0; r < 4; r++)
      Og[(size_t)(b * 2048 + q0 + lc) * 1024 + h * 64 + vf * 16 + qr * 4 + r] =
          f2bf(o_acc[vf][r] * inv);
}

extern "C" void kernel_launch(void* const* d_in, const int* in_sizes, int n_in,
                              void* d_out, int out_size, void* d_ws, size_t ws_size,
                              hipStream_t stream) {
  (void)in_sizes; (void)n_in; (void)out_size; (void)ws_size;
  const float* x1 = (const float*)d_in[0];
  const float* x2 = (const float*)d_in[1];
  const float* Wm = (const float*)d_in[2];
  const int* mask = (const int*)d_in[3];
  const float* Wq = (const float*)d_in[4];
  const float* Wk = (const float*)d_in[5];
  const float* Wv = (const float*)d_in[6];
  const float* Wo = (const float*)d_in[7];
  const float* bo = (const float*)d_in[8];

  char* ws = (char*)d_ws;
  const size_t SZ_X = (size_t)4096 * 1024 * 2;   // 8 MB bf16 activation
  const size_t SZ_W = (size_t)1024 * 1024 * 2;   // 2 MB bf16 weight
  unsigned short* Wqb = (unsigned short*)(ws + 0);
  unsigned short* Wkb = (unsigned short*)(ws + SZ_W);
  unsigned short* Wvb = (unsigned short*)(ws + 2 * SZ_W);
  unsigned short* Wob = (unsigned short*)(ws + 3 * SZ_W);
  unsigned short* Qb  = (unsigned short*)(ws + 4 * SZ_W);
  unsigned short* Kb  = (unsigned short*)(ws + 4 * SZ_W + SZ_X);
  unsigned short* Vtb = (unsigned short*)(ws + 4 * SZ_W + 2 * SZ_X);
  unsigned short* Ob  = (unsigned short*)(ws + 4 * SZ_W + 3 * SZ_X);

  cvt_kernel<<<512, 256, 0, stream>>>(Wq, Wqb, 1024 * 1024 / 4);
  cvt_kernel<<<512, 256, 0, stream>>>(Wk, Wkb, 1024 * 1024 / 4);
  cvt_kernel<<<512, 256, 0, stream>>>(Wv, Wvb, 1024 * 1024 / 4);
  cvt_kernel<<<512, 256, 0, stream>>>(Wo, Wob, 1024 * 1024 / 4);

  dim3 gg(32, 16);
  gemm_bt<0, 1><<<gg, 256, 0, stream>>>(x1, Wqb, Qb, nullptr, nullptr, 0.125f, 4096, 1024, 1024);
  gemm_bt<0, 1><<<gg, 256, 0, stream>>>(x2, Wkb, Kb, nullptr, nullptr, 1.0f, 4096, 1024, 1024);
  gemm_bt<1, 1><<<gg, 256, 0, stream>>>(x2, Wvb, Vtb, nullptr, nullptr, 1.0f, 4096, 1024, 1024);

  flash_kernel<<<1024, 256, 0, stream>>>(Qb, Kb, Vtb, Wm, mask, Ob);

  gemm_bt<2, 0><<<gg, 256, 0, stream>>>(Ob, Wob, nullptr, (float*)d_out, bo, 1.0f, 4096, 1024, 1024);
}

// Round 7
// 272.063 us; speedup vs baseline: 1.7182x; 1.7182x over previous
//
#include <hip/hip_runtime.h>
#include <hip/hip_bf16.h>
#include <stdint.h>

typedef __attribute__((ext_vector_type(4))) float f32x4;
typedef __attribute__((ext_vector_type(8))) short bf16x8;
typedef __attribute__((ext_vector_type(8))) unsigned short u16x8;

__device__ __forceinline__ unsigned short f2bf(float f) {
  unsigned int u = __float_as_uint(f);
  u += 0x7fffu + ((u >> 16) & 1u);   // round-to-nearest-even
  return (unsigned short)(u >> 16);
}

__device__ __forceinline__ unsigned int pk_bf16(float lo, float hi) {
  unsigned int r;
  asm("v_cvt_pk_bf16_f32 %0, %1, %2" : "=v"(r) : "v"(lo), "v"(hi));
  return r;
}

__device__ __forceinline__ void gld16(const void* g, void* l) {
  __builtin_amdgcn_global_load_lds(
      (const __attribute__((address_space(1))) unsigned int*)g,
      (__attribute__((address_space(3))) unsigned int*)l, 16, 0, 0);
}

__global__ __launch_bounds__(256) void cvt_kernel(const float* __restrict__ in,
                                                  unsigned short* __restrict__ out, int n4) {
  int stride = gridDim.x * blockDim.x;
  for (int i = blockIdx.x * blockDim.x + threadIdx.x; i < n4; i += stride) {
    float4 v = reinterpret_cast<const float4*>(in)[i];
    ushort4 o;
    o.x = f2bf(v.x); o.y = f2bf(v.y); o.z = f2bf(v.z); o.w = f2bf(v.w);
    reinterpret_cast<ushort4*>(out)[i] = o;
  }
}

// C = A[M,Kd] * Bt[N,Kd]^T ; bf16 inputs, f32 accumulate. BM=BN=128.
// EPI 0: bf16 store row-major, value*scl
// EPI 1: V-transpose bf16 store: dst[(b*1024 + n)*2048 + (m&2047)]
// EPI 2: f32 store row-major with +bias[n]  (final output)
template <int EPI>
__global__ __launch_bounds__(256) void gemm_bt(const unsigned short* __restrict__ A,
                                               const unsigned short* __restrict__ Bt,
                                               unsigned short* __restrict__ C,
                                               float* __restrict__ Cf,
                                               const float* __restrict__ bias,
                                               float scl, int M, int N, int Kd) {
  __shared__ unsigned short As[128 * 64];
  __shared__ unsigned short Bs[128 * 64];
  const int tid = threadIdx.x;
  const int lane = tid & 63;
  const int wid = tid >> 6;
  const int wm = wid >> 1, wn = wid & 1;
  const int lc = lane & 15, qr = lane >> 4;
  const int m0 = blockIdx.x * 128, n0 = blockIdx.y * 128;

  f32x4 acc[4][4];
#pragma unroll
  for (int i = 0; i < 4; i++)
#pragma unroll
    for (int j = 0; j < 4; j++) acc[i][j] = (f32x4)0.0f;

  for (int k0 = 0; k0 < Kd; k0 += 64) {
#pragma unroll
    for (int i = 0; i < 4; i++) {
      int c = i * 256 + tid;
      int row = c >> 3;
      int col = (c & 7) << 3;
      *reinterpret_cast<u16x8*>(&As[row * 64 + col]) =
          *reinterpret_cast<const u16x8*>(&A[(size_t)(m0 + row) * Kd + k0 + col]);
      *reinterpret_cast<u16x8*>(&Bs[row * 64 + col]) =
          *reinterpret_cast<const u16x8*>(&Bt[(size_t)(n0 + row) * Kd + k0 + col]);
    }
    __syncthreads();
#pragma unroll
    for (int kk = 0; kk < 2; kk++) {
      bf16x8 a[4], b[4];
#pragma unroll
      for (int mf = 0; mf < 4; mf++)
        a[mf] = *reinterpret_cast<const bf16x8*>(&As[(wm * 64 + mf * 16 + lc) * 64 + kk * 32 + qr * 8]);
#pragma unroll
      for (int nf = 0; nf < 4; nf++)
        b[nf] = *reinterpret_cast<const bf16x8*>(&Bs[(wn * 64 + nf * 16 + lc) * 64 + kk * 32 + qr * 8]);
#pragma unroll
      for (int mf = 0; mf < 4; mf++)
#pragma unroll
        for (int nf = 0; nf < 4; nf++)
          acc[mf][nf] = __builtin_amdgcn_mfma_f32_16x16x32_bf16(a[mf], b[nf], acc[mf][nf], 0, 0, 0);
    }
    __syncthreads();
  }

#pragma unroll
  for (int mf = 0; mf < 4; mf++) {
#pragma unroll
    for (int nf = 0; nf < 4; nf++) {
      const int row0 = m0 + wm * 64 + mf * 16 + qr * 4;
      const int col = n0 + wn * 64 + nf * 16 + lc;
#pragma unroll
      for (int r = 0; r < 4; r++) {
        float v = acc[mf][nf][r];
        int row = row0 + r;
        if (EPI == 0) {
          C[(size_t)row * N + col] = f2bf(v * scl);
        } else if (EPI == 1) {
          int bb = row >> 11, s2 = row & 2047;
          C[((size_t)(bb * 1024 + col)) * 2048 + s2] = f2bf(v);
        } else {
          Cf[(size_t)row * N + col] = v + bias[col];
        }
      }
    }
  }
}

// Swapped-operand flash cross-attention (math verified in round 6):
// S^T = mfma(K, Q): lane owns one q-row (lc) -> scalar softmax state.
// K/V tiles staged cooperatively into LDS (shared by all 8 waves) via
// global_load_lds, double-buffered, XOR-swizzled (pre-swizzled global src +
// swizzled ds_read: rule "both sides or neither"). W per-lane nontemporal
// dwordx4, register double-buffered. One __syncthreads per tile = pipeline.
// grid 512 blocks (XCD-swizzled: 4 head-batches per XCD), 512 thr = 8 waves.
__global__ __launch_bounds__(512, 4) void flash_kernel(const unsigned short* __restrict__ Qg,
                                                       const unsigned short* __restrict__ Kg,
                                                       const unsigned short* __restrict__ Vt,
                                                       const float* __restrict__ Wm,
                                                       const int* __restrict__ mask,
                                                       unsigned short* __restrict__ Og) {
  __shared__ __attribute__((aligned(16))) unsigned short K_lds[2][64][64];  // [buf][s][k] 8KB/buf
  __shared__ __attribute__((aligned(16))) unsigned short V_lds[2][64][64];  // [buf][v][s] 8KB/buf
  __shared__ unsigned short P_lds[8][16][72];                               // per-wave P
  const int tid = threadIdx.x;
  const int lane = tid & 63;
  const int wid = tid >> 6;
  const int lc = lane & 15, qr = lane >> 4;

  const int bx = blockIdx.x;
  const int nid = (bx & 7) * 64 + (bx >> 3);      // XCD swizzle (512 = 8*64, bijective)
  const int b = nid >> 8, h = (nid >> 4) & 15, qt = nid & 15;
  const int q0 = qt * 128 + wid * 16;

  // Q fragments (B-operand): lane holds Q[q=lc][k=kk*32+qr*8+j]; Q pre-scaled 0.125
  bf16x8 aq[2];
#pragma unroll
  for (int kk = 0; kk < 2; kk++)
    aq[kk] = *reinterpret_cast<const bf16x8*>(
        &Qg[(size_t)(b * 2048 + q0 + lc) * 1024 + h * 64 + kk * 32 + qr * 8]);

  const float mbias = mask[b * 2048 + q0 + lc] ? 0.0f : -INFINITY;

  float m_run = -INFINITY, l_run = 0.0f;
  f32x4 o_acc[4];
#pragma unroll
  for (int vf = 0; vf < 4; vf++) o_acc[vf] = (f32x4)0.0f;

  // byte bases
  const char* KbB = (const char*)Kg + (size_t)b * 2048 * 2048 + h * 128;        // + s*2048 + colB
  const char* VbB = (const char*)Vt + ((size_t)b * 1024 + h * 64) * 4096;        // + v*4096 + s*2
  const float* wrow = Wm + ((size_t)((b * 16 + h) * 2048 + q0 + lc)) * 2048 + qr * 4;

  // staging geometry: thread writes LDS linear bytes tid*16 (row=tid>>3, 128B rows);
  // SOURCE col is pre-swizzled so that LDS[row][x] = G[row][x ^ ((row&7)<<4)]
  const int strow = tid >> 3;
  const int stcol = ((tid & 7) * 16) ^ ((strow & 7) << 4);
  const char* kst = KbB + (size_t)strow * 2048 + stcol;   // + s0*2048
  const char* vst = VbB + (size_t)strow * 4096 + stcol;   // + s0*2
  char* kdst = (char*)K_lds + wid * 1024;                 // + buf*8192 (lane*16 auto)
  char* vdst = (char*)V_lds + wid * 1024;
  const int rsw = (lc & 7) << 4;                          // read-side swizzle

  f32x4 wA[4], wB[4];   // W dbuf: w[f][r] = W[q0+lc][s0 + f*16 + qr*4 + r]

#define STAGEKV(TB, S0)                                                      \
  gld16(kst + (size_t)(S0) * 2048, kdst + (TB) * 8192);                      \
  gld16(vst + (size_t)(S0) * 2, vdst + (TB) * 8192);

#define LOADW(S0, W)                                                         \
  _Pragma("unroll") for (int f = 0; f < 4; f++)                              \
      W[f] = __builtin_nontemporal_load(                                     \
          reinterpret_cast<const f32x4*>(wrow + (S0) + f * 16));

#define TILE(T, BUF, WC, WN)                                                 \
  {                                                                          \
    if ((T) < 31) { STAGEKV((BUF) ^ 1, ((T) + 1) * 64); LOADW(((T) + 1) * 64, WN); } \
    const char* kb = (const char*)K_lds + (BUF) * 8192;                      \
    const char* vb = (const char*)V_lds + (BUF) * 8192;                      \
    f32x4 sacc[4];                                                           \
    _Pragma("unroll") for (int f = 0; f < 4; f++) sacc[f] = (f32x4)0.0f;     \
    _Pragma("unroll") for (int f = 0; f < 4; f++)                            \
    _Pragma("unroll") for (int kk = 0; kk < 2; kk++) {                       \
      bf16x8 kf = *reinterpret_cast<const bf16x8*>(                          \
          kb + (f * 16 + lc) * 128 + ((kk * 64 + qr * 16) ^ rsw));           \
      sacc[f] = __builtin_amdgcn_mfma_f32_16x16x32_bf16(kf, aq[kk], sacc[f], 0, 0, 0); \
    }                                                                        \
    float tm = -INFINITY;                                                    \
    _Pragma("unroll") for (int f = 0; f < 4; f++)                            \
    _Pragma("unroll") for (int r = 0; r < 4; r++) {                          \
      float v = fmaf(sacc[f][r], WC[f][r], mbias);                           \
      sacc[f][r] = v;                                                        \
      tm = fmaxf(tm, v);                                                     \
    }                                                                        \
    tm = fmaxf(tm, __shfl_xor(tm, 16));                                      \
    tm = fmaxf(tm, __shfl_xor(tm, 32));                                      \
    const float mn = fmaxf(m_run, tm);                                       \
    const float sc = __expf(m_run - mn);                                     \
    m_run = mn;                                                              \
    float rs = 0.0f;                                                         \
    _Pragma("unroll") for (int f = 0; f < 4; f++)                            \
    _Pragma("unroll") for (int r = 0; r < 4; r++) {                          \
      float p = __expf(sacc[f][r] - mn);                                     \
      sacc[f][r] = p;                                                        \
      rs += p;                                                               \
    }                                                                        \
    rs += __shfl_xor(rs, 16);                                                \
    rs += __shfl_xor(rs, 32);                                                \
    l_run = l_run * sc + rs;                                                 \
    _Pragma("unroll") for (int vf = 0; vf < 4; vf++)                         \
    _Pragma("unroll") for (int r = 0; r < 4; r++) o_acc[vf][r] *= sc;        \
    _Pragma("unroll") for (int f = 0; f < 4; f++) {                          \
      unsigned int u0 = pk_bf16(sacc[f][0], sacc[f][1]);                     \
      unsigned int u1 = pk_bf16(sacc[f][2], sacc[f][3]);                     \
      const int kbse = f * 16 + qr * 4;                                      \
      *reinterpret_cast<unsigned int*>(&P_lds[wid][lc][kbse]) = u0;          \
      *reinterpret_cast<unsigned int*>(&P_lds[wid][lc][kbse + 2]) = u1;      \
    }                                                                        \
    _Pragma("unroll") for (int kk = 0; kk < 2; kk++) {                       \
      bf16x8 pb = *reinterpret_cast<const bf16x8*>(                          \
          &P_lds[wid][lc][kk * 32 + qr * 8]);                                \
      _Pragma("unroll") for (int vf = 0; vf < 4; vf++) {                     \
        bf16x8 vr = *reinterpret_cast<const bf16x8*>(                        \
            vb + (vf * 16 + lc) * 128 + ((kk * 64 + qr * 16) ^ rsw));        \
        o_acc[vf] = __builtin_amdgcn_mfma_f32_16x16x32_bf16(vr, pb, o_acc[vf], 0, 0, 0); \
      }                                                                      \
    }                                                                        \
    __syncthreads();                                                         \
  }

  STAGEKV(0, 0);
  LOADW(0, wA);
  __syncthreads();
#pragma unroll 1
  for (int t = 0; t < 32; t += 2) {
    TILE(t, 0, wA, wB);
    TILE(t + 1, 1, wB, wA);
  }

  const float inv = 1.0f / l_run;
#pragma unroll
  for (int vf = 0; vf < 4; vf++)
#pragma unroll
    for (int r = 0; r < 4; r++)
      Og[(size_t)(b * 2048 + q0 + lc) * 1024 + h * 64 + vf * 16 + qr * 4 + r] =
          f2bf(o_acc[vf][r] * inv);
}

extern "C" void kernel_launch(void* const* d_in, const int* in_sizes, int n_in,
                              void* d_out, int out_size, void* d_ws, size_t ws_size,
                              hipStream_t stream) {
  (void)in_sizes; (void)n_in; (void)out_size; (void)ws_size;
  const float* x1 = (const float*)d_in[0];
  const float* x2 = (const float*)d_in[1];
  const float* Wm = (const float*)d_in[2];
  const int* mask = (const int*)d_in[3];
  const float* Wq = (const float*)d_in[4];
  const float* Wk = (const float*)d_in[5];
  const float* Wv = (const float*)d_in[6];
  const float* Wo = (const float*)d_in[7];
  const float* bo = (const float*)d_in[8];

  char* ws = (char*)d_ws;
  const size_t SZ_X = (size_t)4096 * 1024 * 2;   // 8 MB bf16 activation
  const size_t SZ_W = (size_t)1024 * 1024 * 2;   // 2 MB bf16 weight
  unsigned short* x1b = (unsigned short*)(ws + 0);
  unsigned short* x2b = (unsigned short*)(ws + SZ_X);
  unsigned short* Wqb = (unsigned short*)(ws + 2 * SZ_X);
  unsigned short* Wkb = (unsigned short*)(ws + 2 * SZ_X + SZ_W);
  unsigned short* Wvb = (unsigned short*)(ws + 2 * SZ_X + 2 * SZ_W);
  unsigned short* Wob = (unsigned short*)(ws + 2 * SZ_X + 3 * SZ_W);
  unsigned short* Qb  = (unsigned short*)(ws + 2 * SZ_X + 4 * SZ_W);
  unsigned short* Kb  = (unsigned short*)(ws + 3 * SZ_X + 4 * SZ_W);
  unsigned short* Vtb = (unsigned short*)(ws + 4 * SZ_X + 4 * SZ_W);
  unsigned short* Ob  = (unsigned short*)(ws + 5 * SZ_X + 4 * SZ_W);

  cvt_kernel<<<2048, 256, 0, stream>>>(x1, x1b, 4096 * 1024 / 4);
  cvt_kernel<<<2048, 256, 0, stream>>>(x2, x2b, 4096 * 1024 / 4);
  cvt_kernel<<<512, 256, 0, stream>>>(Wq, Wqb, 1024 * 1024 / 4);
  cvt_kernel<<<512, 256, 0, stream>>>(Wk, Wkb, 1024 * 1024 / 4);
  cvt_kernel<<<512, 256, 0, stream>>>(Wv, Wvb, 1024 * 1024 / 4);
  cvt_kernel<<<512, 256, 0, stream>>>(Wo, Wob, 1024 * 1024 / 4);

  dim3 gg(32, 8);
  gemm_bt<0><<<gg, 256, 0, stream>>>(x1b, Wqb, Qb, nullptr, nullptr, 0.125f, 4096, 1024, 1024);
  gemm_bt<0><<<gg, 256, 0, stream>>>(x2b, Wkb, Kb, nullptr, nullptr, 1.0f, 4096, 1024, 1024);
  gemm_bt<1><<<gg, 256, 0, stream>>>(x2b, Wvb, Vtb, nullptr, nullptr, 1.0f, 4096, 1024, 1024);

  flash_kernel<<<512, 512, 0, stream>>>(Qb, Kb, Vtb, Wm, mask, Ob);

  gemm_bt<2><<<gg, 256, 0, stream>>>(Ob, Wob, nullptr, (float*)d_out, bo, 1.0f, 4096, 1024, 1024);
}